// Round 13
// baseline (253.764 us; speedup 1.0000x reference)
//
#include <hip/hip_runtime.h>
#include <hip/hip_bf16.h>
#include <hip/hip_fp16.h>

// Problem constants
#define B_   2
#define T_   2048
#define DM   2048
#define NH   16
#define DH   128
#define M_   (B_*T_)          // 4096 rows
#define SCALE_ 0.08838834764831845f   // 1/sqrt(128)

typedef _Float16 f16;
typedef f16  half8 __attribute__((ext_vector_type(8)));
typedef f16  half4 __attribute__((ext_vector_type(4)));
typedef float f32x4 __attribute__((ext_vector_type(4)));

#define GL16(gp, lp) __builtin_amdgcn_global_load_lds( \
    (const __attribute__((address_space(1))) void*)(gp), \
    (__attribute__((address_space(3))) void*)(lp), 16, 0, 0)

#define MFMA16(a, b, c) __builtin_amdgcn_mfma_f32_16x16x32_f16((a), (b), (c), 0, 0, 0)

// ---------------- fused fp32 -> fp16 convert (one launch for all 5) ----------------
struct CvtArgs { const float* s[5]; f16* d[5]; };

__global__ __launch_bounds__(256) void convert_all(CvtArgs a) {
    size_t i4 = (size_t)blockIdx.x * 256 + threadIdx.x;
    int r; size_t off;
    if (i4 < 2097152) { r = 0; off = i4; }
    else { size_t k = i4 - 2097152; r = 1 + (int)(k >> 20); off = k & 1048575; }
    float4 v = *((const float4*)a.s[r] + off);
    half4 h;
    h[0] = (f16)v.x; h[1] = (f16)v.y; h[2] = (f16)v.z; h[3] = (f16)v.w;
    *((half4*)a.d[r] + off) = h;
}

// ============ fused QKV GEMM: 256x192, BK=64 (R3 structure, frozen) ============
// R13: V section (sec==2) written directly TRANSPOSED ([B,H,DH,T]) in the
// epilogue — absorbs the former vtrans kernel (~4 us + launch gap) for free.
// Per-element index math only; tile structure/sync untouched. j-loop locality
// actually improves for V (consecutive j -> consecutive tt -> contiguous 8B).
#define NT_K 32

__global__ __launch_bounds__(512, 2)
void qkv3(const f16* __restrict__ A, const f16* __restrict__ Bw,
          f16* __restrict__ dst)
{
    __shared__ __align__(16) char smem[114688];   // 2 x (32KB A + 24KB B)

    const int tid  = threadIdx.x;
    const int lane = tid & 63;
    const int w    = tid >> 6;
    const int wr   = w >> 1, wc = w & 1;          // 4x2 wave grid

    const int id = (blockIdx.x & 7) * 64 + (blockIdx.x >> 3);
    const int bm = id & 15, bn = id >> 4;
    const int m0 = bm * 256, n0 = bn * 192;

    const int scol8 = (((tid & 7) ^ ((tid >> 3) & 7)) << 3);
    const int rc0 = (((lane >> 4) * 16)      ) ^ ((lane & 7) << 4);
    const int rc1 = (64 + (lane >> 4) * 16   ) ^ ((lane & 7) << 4);

    f32x4 acc[4][6] = {};

#define QSTAGE_A(bufb, ch, s, kt) GL16( \
    A + (size_t)(m0 + (ch)*128 + (tid>>8)*64 + (s)*32 + ((tid>>3)&31)) * 2048 + (kt)*64 + scol8, \
    smem + (bufb)*57344 + (ch)*16384 + (s)*8192 + w*1024)
#define QSTAGE_B(bufb, u, kt) GL16( \
    Bw + (size_t)(n0 + (tid>>7)*48 + (u)*16 + ((tid>>3)&15)) * 2048 + (kt)*64 + scol8, \
    smem + (bufb)*57344 + 32768 + (u)*8192 + w*1024)

    const int abase = (wr >> 1) * 16384 + (wr & 1) * 4096 + (lane & 15) * 128;
    const int bbase = 32768 + wc * 4096 + (lane & 15) * 128;

    half8 af0[4][2], af1[4][2], bnx[2];

    QSTAGE_A(0, 0, 0, 0); QSTAGE_A(0, 0, 1, 0);
    QSTAGE_A(0, 1, 0, 0); QSTAGE_A(0, 1, 1, 0);
    QSTAGE_B(0, 0, 0);    QSTAGE_B(0, 1, 0);    QSTAGE_B(0, 2, 0);
    {
        asm volatile("s_waitcnt vmcnt(2)" ::: "memory");
        __builtin_amdgcn_s_barrier();
        __builtin_amdgcn_sched_barrier(0);
        const char* buf0 = smem;
        #pragma unroll
        for (int m = 0; m < 4; ++m) {
            const char* p = buf0 + (m >> 1) * 8192 + abase + (m & 1) * 2048;
            af0[m][0] = *(const half8*)(p + rc0);
            af0[m][1] = *(const half8*)(p + rc1);
        }
        bnx[0] = *(const half8*)(buf0 + bbase + rc0);
        bnx[1] = *(const half8*)(buf0 + bbase + rc1);
    }

#define GATE(n_) do { \
    asm volatile("s_waitcnt vmcnt(" #n_ ")" ::: "memory"); \
    __builtin_amdgcn_s_barrier(); \
    __builtin_amdgcn_sched_barrier(0); \
} while (0)

#define MFC(AF, BB, f_) do { \
    __builtin_amdgcn_s_setprio(1); \
    _Pragma("unroll") \
    for (int m_ = 0; m_ < 4; ++m_) { \
        acc[m_][f_] = MFMA16(AF[m_][0], (BB)[0], acc[m_][f_]); \
        acc[m_][f_] = MFMA16(AF[m_][1], (BB)[1], acc[m_][f_]); \
    } \
    __builtin_amdgcn_s_setprio(0); \
} while (0)

#define RDB(dstv, off) do { \
    const char* p_ = buf + bbase + (off); \
    dstv[0] = *(const half8*)(p_ + rc0); \
    dstv[1] = *(const half8*)(p_ + rc1); \
} while (0)

#define BODY(t_, c_, AFC, AFN) do { \
    const char* buf  = smem + (c_) * 57344; \
    const char* nbuf = smem + ((c_) ^ 1) * 57344; \
    const int  kt    = ((t_) + 1 < NT_K) ? (t_) + 1 : (t_); \
    half8 b3[2], b1[2], b4[2], b2[2], b5[2]; \
    /* ph0: reads b(f3); stage A0',A1'; MFMA f0 */ \
    RDB(b3, 2048); \
    QSTAGE_A((c_) ^ 1, 0, 0, kt); QSTAGE_A((c_) ^ 1, 0, 1, kt); \
    MFC(AFC, bnx, 0); \
    /* ph1: gate B1; reads b(f1); stage A2',A3'; MFMA f3 */ \
    GATE(3); \
    RDB(b1, 8192); \
    QSTAGE_A((c_) ^ 1, 1, 0, kt); QSTAGE_A((c_) ^ 1, 1, 1, kt); \
    MFC(AFC, b3, 3); \
    /* ph2: reads b(f4); stage B0'; MFMA f1 */ \
    RDB(b4, 8192 + 2048); \
    QSTAGE_B((c_) ^ 1, 0, kt); \
    MFC(AFC, b1, 1); \
    /* ph3: gate B2; reads b(f2); stage B1'; MFMA f4 */ \
    GATE(5); \
    RDB(b2, 16384); \
    QSTAGE_B((c_) ^ 1, 1, kt); \
    MFC(AFC, b4, 4); \
    /* ph4: gate A0-3'+B0'; reads b(f5)+af'[0..1]; stage B2'; MFMA f2 */ \
    GATE(1); \
    RDB(b5, 16384 + 2048); \
    { const char* p_ = nbuf + abase; \
      AFN[0][0] = *(const half8*)(p_ + rc0); \
      AFN[0][1] = *(const half8*)(p_ + rc1); \
      AFN[1][0] = *(const half8*)(p_ + 2048 + rc0); \
      AFN[1][1] = *(const half8*)(p_ + 2048 + rc1); } \
    QSTAGE_B((c_) ^ 1, 2, kt); \
    MFC(AFC, b2, 2); \
    /* ph5: reads af'[2..3] + b'(f0); MFMA f5 */ \
    { const char* p_ = nbuf + 8192 + abase; \
      AFN[2][0] = *(const half8*)(p_ + rc0); \
      AFN[2][1] = *(const half8*)(p_ + rc1); \
      AFN[3][0] = *(const half8*)(p_ + 2048 + rc0); \
      AFN[3][1] = *(const half8*)(p_ + 2048 + rc1); } \
    { const char* p_ = nbuf + bbase; \
      bnx[0] = *(const half8*)(p_ + rc0); \
      bnx[1] = *(const half8*)(p_ + rc1); } \
    MFC(AFC, b5, 5); \
} while (0)

    for (int t = 0; t < NT_K; t += 2) {
        BODY(t,     0, af0, af1);
        BODY(t + 1, 1, af1, af0);
    }
#undef BODY
#undef RDB
#undef MFC
#undef GATE
#undef QSTAGE_A
#undef QSTAGE_B

    asm volatile("s_waitcnt vmcnt(0)" ::: "memory");

    #pragma unroll
    for (int m = 0; m < 4; ++m)
        #pragma unroll
        for (int f = 0; f < 6; ++f)
            #pragma unroll
            for (int j = 0; j < 4; ++j) {
                int row  = m0 + wr * 64 + m * 16 + (lane >> 4) * 4 + j;
                int gcol = n0 + wc * 96 + f * 16 + (lane & 15);
                int sec = gcol >> 11, cic = gcol & 2047;
                int b = row >> 11, tt = row & (T_ - 1);
                int h = cic >> 7, d = cic & 127;
                float cs = (sec == 0) ? SCALE_ : 1.0f;
                // Q,K: [B,H,T,DH]; V (sec==2): written TRANSPOSED [B,H,DH,T]
                size_t off = (sec == 2)
                    ? (size_t)2 * ((size_t)M_ * 2048) +
                      ((size_t)(b * NH + h) * DH + d) * T_ + tt
                    : (size_t)sec * ((size_t)M_ * 2048) +
                      ((size_t)(b * NH + h) * T_ + tt) * DH + d;
                dst[off] = (f16)(acc[m][f][j] * cs);
            }
}

// ============ W_o GEMM: 256x128, BK=64, 2-gate (R9 version — best measured) ============
#define NT_W 32

__global__ __launch_bounds__(512, 2)
void wo2(const f16* __restrict__ A, const f16* __restrict__ Bw,
         float* __restrict__ Cf)
{
    __shared__ __align__(16) char smem[98304];   // 2 x (32KB A + 16KB B)

    const int tid  = threadIdx.x;
    const int lane = tid & 63;
    const int w    = tid >> 6;
    const int wr   = w >> 1, wc = w & 1;          // 4x2 wave grid, wave 64x64

    const int id = (blockIdx.x & 7) * 32 + (blockIdx.x >> 3);
    const int bm = id & 15, bn = id >> 4;
    const int m0 = bm * 256, n0 = bn * 128;

    const int scol8 = (((tid & 7) ^ ((tid >> 3) & 7)) << 3);
    const int rc0 = (((lane >> 4) * 16)      ) ^ ((lane & 7) << 4);
    const int rc1 = (64 + (lane >> 4) * 16   ) ^ ((lane & 7) << 4);

    f32x4 acc[4][4] = {};

#define WSA(bufb, s, kt) GL16( \
    A + (size_t)(m0 + ((s)&1)*128 + (tid>>8)*64 + ((s)>>1)*32 + ((tid>>3)&31)) * 2048 + (kt)*64 + scol8, \
    smem + (bufb)*49152 + (s)*8192 + w*1024)
#define WSB(bufb, u, kt) GL16( \
    Bw + (size_t)(n0 + (tid>>8)*64 + (u)*32 + ((tid>>3)&31)) * 2048 + (kt)*64 + scol8, \
    smem + (bufb)*49152 + 32768 + (u)*8192 + w*1024)

    WSA(0, 0, 0); WSA(0, 1, 0); WSB(0, 0, 0); WSB(0, 1, 0);
    WSA(0, 2, 0); WSA(0, 3, 0);

    const int abase = (wr >> 1) * 8192 + (wr & 1) * 4096 + (lane & 15) * 128;
    const int bbase = 32768 + wc * 4096 + (lane & 15) * 128;

#define WGATE(n_) do { \
    asm volatile("s_waitcnt vmcnt(" #n_ ")" ::: "memory"); \
    __builtin_amdgcn_s_barrier(); \
    __builtin_amdgcn_sched_barrier(0); \
} while (0)

    for (int t = 0; t < NT_W; ++t) {
        const int c = t & 1;
        const char* buf = smem + c * 49152;
        const int kt = (t + 1 < NT_W) ? t + 1 : t;

        half8 af[4][2], bf[4][2];

        // ---- phase 0: m=0,1 ----
        WGATE(2);
        #pragma unroll
        for (int m = 0; m < 2; ++m) {
            const char* p = buf + abase + m * 2048;
            af[m][0] = *(const half8*)(p + rc0);
            af[m][1] = *(const half8*)(p + rc1);
        }
        #pragma unroll
        for (int n = 0; n < 4; ++n) {
            const char* p = buf + bbase + (n >> 1) * 8192 + (n & 1) * 2048;
            bf[n][0] = *(const half8*)(p + rc0);
            bf[n][1] = *(const half8*)(p + rc1);
        }
        WSA(c ^ 1, 0, kt); WSA(c ^ 1, 1, kt);
        WSB(c ^ 1, 0, kt); WSB(c ^ 1, 1, kt);
        __builtin_amdgcn_s_setprio(1);
        #pragma unroll
        for (int m = 0; m < 2; ++m)
            #pragma unroll
            for (int n = 0; n < 4; ++n) {
                acc[m][n] = MFMA16(af[m][0], bf[n][0], acc[m][n]);
                acc[m][n] = MFMA16(af[m][1], bf[n][1], acc[m][n]);
            }
        __builtin_amdgcn_s_setprio(0);

        // ---- phase 1: m=2,3 ----
        WGATE(4);
        #pragma unroll
        for (int m = 2; m < 4; ++m) {
            const char* p = buf + 16384 + abase + (m & 1) * 2048;
            af[m][0] = *(const half8*)(p + rc0);
            af[m][1] = *(const half8*)(p + rc1);
        }
        WSA(c ^ 1, 2, kt); WSA(c ^ 1, 3, kt);
        __builtin_amdgcn_s_setprio(1);
        #pragma unroll
        for (int m = 2; m < 4; ++m)
            #pragma unroll
            for (int n = 0; n < 4; ++n) {
                acc[m][n] = MFMA16(af[m][0], bf[n][0], acc[m][n]);
                acc[m][n] = MFMA16(af[m][1], bf[n][1], acc[m][n]);
            }
        __builtin_amdgcn_s_setprio(0);
    }
#undef WGATE
#undef WSA
#undef WSB

    asm volatile("s_waitcnt vmcnt(0)" ::: "memory");

    #pragma unroll
    for (int m = 0; m < 4; ++m)
        #pragma unroll
        for (int n = 0; n < 4; ++n)
            #pragma unroll
            for (int j = 0; j < 4; ++j) {
                int row = m0 + wr * 64 + m * 16 + (lane >> 4) * 4 + j;
                int col = n0 + wc * 64 + n * 16 + (lane & 15);
                Cf[(size_t)row * 2048 + col] = acc[m][n][j];
            }
}

// ---------------- causal flash attention: mirror-pair + softmax cuts (R7 exact) ----------------
#define QB 64
#define KB 64
#define PP 72
#define NQT (T_/QB)   // 32

__global__ __launch_bounds__(256, 2)
void attn_fwd(const f16* __restrict__ Q, const f16* __restrict__ K,
              const f16* __restrict__ Vt, f16* __restrict__ O)
{
    __shared__ __align__(16) char Ks[2][16384];   // 64 k-rows x 256B (swz)
    __shared__ __align__(16) char Vs[2][16384];   // 128 d-rows x 128B (swz)
    __shared__ __align__(16) f16 Ps[4][16][PP];

    const int tid  = threadIdx.x;
    const int lane = tid & 63;
    const int w    = tid >> 6;
    const int g    = lane >> 4;

    const int bid  = blockIdx.x;
    const int swz  = (bid & 7) * 64 + (bid >> 3);
    const int bh   = swz >> 4;
    const int pair = swz & 15;
    const size_t base = (size_t)bh * T_ * DH;     // == bh*DH*T_ (V^T base)
    const int b = bh >> 4, h = bh & 15;

    const int krow0 = w * 4 + g;
    const int kswz  = ((lane & 15) ^ (krow0 & 7)) << 3;          // elems
    const int vrow0 = w * 8 + (lane >> 3);
    const int vswz  = (((lane & 7) ^ ((lane >> 3) & 7)) << 3);   // elems

#define STAGE_K(c_, kv) do { \
    _Pragma("unroll") for (int i_ = 0; i_ < 4; ++i_) { \
        const f16* g_ = K + base + (size_t)((kv) + i_*16 + krow0) * DH + kswz; \
        GL16(g_, &Ks[c_][i_*4096 + w*1024]); } } while (0)
#define STAGE_V(c_, kv) do { \
    _Pragma("unroll") for (int i_ = 0; i_ < 4; ++i_) { \
        const f16* g_ = Vt + base + (size_t)(i_*32 + vrow0) * T_ + (kv) + vswz; \
        GL16(g_, &Vs[c_][i_*4096 + w*1024]); } } while (0)

#define QKT(SA, QF) do { \
    __builtin_amdgcn_s_setprio(1); \
    _Pragma("unroll") \
    for (int n_ = 0; n_ < 4; ++n_) \
        _Pragma("unroll") \
        for (int kk_ = 0; kk_ < 4; ++kk_) { \
            half8 kfv = *(const half8*)(kb + (n_*16 + (lane & 15)) * 256 + \
                ((kk_*32 + g * 8) * 2 ^ ((lane & 7) << 4))); \
            SA[n_] = MFMA16(kfv, QF[kk_], SA[n_]); \
        } \
    __builtin_amdgcn_s_setprio(0); \
} while (0)

#define SMAX(SA, MRUN, LSUM, OO) do { \
    float mx_ = SA[0][0]; \
    _Pragma("unroll") \
    for (int n_ = 0; n_ < 4; ++n_) \
        _Pragma("unroll") \
        for (int j_ = 0; j_ < 4; ++j_) mx_ = fmaxf(mx_, SA[n_][j_]); \
    mx_ = fmaxf(mx_, __shfl_xor(mx_, 16)); \
    mx_ = fmaxf(mx_, __shfl_xor(mx_, 32)); \
    if (!__all(mx_ <= MRUN + 5.f)) { \
        float mnew_ = fmaxf(MRUN, mx_); \
        float sf_ = __expf(MRUN - mnew_); \
        _Pragma("unroll") \
        for (int nn_ = 0; nn_ < 8; ++nn_) OO[nn_] *= sf_; \
        LSUM *= sf_; \
        MRUN = mnew_; \
    } \
    float rs_ = 0.f; \
    _Pragma("unroll") \
    for (int n_ = 0; n_ < 4; ++n_) \
        _Pragma("unroll") \
        for (int j_ = 0; j_ < 4; ++j_) { \
            float p_ = __expf(SA[n_][j_] - MRUN); \
            SA[n_][j_] = p_; \
            rs_ += p_; \
        } \
    LSUM += rs_; \
} while (0)

#define PFRAG(SA, BP) do { \
    _Pragma("unroll") \
    for (int n_ = 0; n_ < 4; ++n_) { \
        half4 hv_; \
        hv_[0] = (f16)SA[n_][0]; hv_[1] = (f16)SA[n_][1]; \
        hv_[2] = (f16)SA[n_][2]; hv_[3] = (f16)SA[n_][3]; \
        *reinterpret_cast<half4*>(&Ps[w][lane & 15][n_*16 + g*4]) = hv_; \
    } \
    _Pragma("unroll") \
    for (int cc_ = 0; cc_ < 2; ++cc_) \
        BP[cc_] = *reinterpret_cast<const half8*>(&Ps[w][lane & 15][cc_*32 + g*8]); \
} while (0)

#define PV(OO, BP) do { \
    __builtin_amdgcn_s_setprio(1); \
    _Pragma("unroll") \
    for (int n_ = 0; n_ < 8; ++n_) \
        _Pragma("unroll") \
        for (int cc_ = 0; cc_ < 2; ++cc_) { \
            half8 vf_ = *(const half8*)(vb + (n_*16 + (lane & 15)) * 128 + \
                ((cc_*64 + g*16) ^ ((lane & 7) << 4))); \
            OO[n_] = MFMA16(vf_, BP[cc_], OO[n_]); \
        } \
    __builtin_amdgcn_s_setprio(0); \
} while (0)

    const int qt1 = pair;              // small member
    const int qt2 = NQT - 1 - pair;    // big member
    const int nt1 = qt1 + 1;           // set1 kv-tiles
    const int ntU = qt2 + 1;           // union kv-tiles (= set2's)
    const int qg1 = qt1 * QB + w * 16 + (lane & 15);
    const int qg2 = qt2 * QB + w * 16 + (lane & 15);

    half8 qf1[4], qf2[4];
    #pragma unroll
    for (int kk = 0; kk < 4; ++kk) {
        qf1[kk] = *reinterpret_cast<const half8*>(
            &Q[base + (size_t)qg1 * DH + kk * 32 + g * 8]);
        qf2[kk] = *reinterpret_cast<const half8*>(
            &Q[base + (size_t)qg2 * DH + kk * 32 + g * 8]);
    }

    float mrun1 = -1e30f, lsum1 = 0.f;
    float mrun2 = -1e30f, lsum2 = 0.f;
    f32x4 o1[8] = {};
    f32x4 o2[8] = {};

    STAGE_K(0, 0);
    STAGE_V(0, 0);

    for (int it = 0; it < ntU; ++it) {
        const int c = it & 1;
        __syncthreads();      // vmcnt(0) drain: tile-it K/V resident
        if (it + 1 < ntU) {
            STAGE_K(c ^ 1, (it + 1) * KB);
            STAGE_V(c ^ 1, (it + 1) * KB);
        }
        const bool s1 = (it < nt1);    // block-uniform
        const char* kb = &Ks[c][0];
        const char* vb = &Vs[c][0];

        f32x4 sa2[4] = {};
        f32x4 sa1[4] = {};

        QKT(sa2, qf2);
        if (s1) QKT(sa1, qf1);

        if (it == ntU - 1) {
            #pragma unroll
            for (int n = 0; n < 4; ++n)
                #pragma unroll
                for (int j = 0; j < 4; ++j) {
                    int kg = it * KB + n*16 + g*4 + j;
                    if (kg > qg2) sa2[n][j] = -1e30f;
                }
        }
        if (s1 && it == nt1 - 1) {
            #pragma unroll
            for (int n = 0; n < 4; ++n)
                #pragma unroll
                for (int j = 0; j < 4; ++j) {
                    int kg = it * KB + n*16 + g*4 + j;
                    if (kg > qg1) sa1[n][j] = -1e30f;
                }
        }

        SMAX(sa2, mrun2, lsum2, o2);
        half8 bp2[2];
        PFRAG(sa2, bp2);
        PV(o2, bp2);

        if (s1) {
            SMAX(sa1, mrun1, lsum1, o1);
            half8 bp1[2];
            PFRAG(sa1, bp1);
            PV(o1, bp1);
        }
    }

    {
        float l2 = lsum2;
        l2 += __shfl_xor(l2, 16);
        l2 += __shfl_xor(l2, 32);
        float invl = 1.0f / l2;
        #pragma unroll
        for (int n = 0; n < 8; ++n) {
            half4 hv;
            hv[0] = (f16)(o2[n][0] * invl); hv[1] = (f16)(o2[n][1] * invl);
            hv[2] = (f16)(o2[n][2] * invl); hv[3] = (f16)(o2[n][3] * invl);
            *reinterpret_cast<half4*>(
                &O[((size_t)(b * T_ + qg2) * NH + h) * DH + n*16 + g*4]) = hv;
        }
    }
    {
        float l1 = lsum1;
        l1 += __shfl_xor(l1, 16);
        l1 += __shfl_xor(l1, 32);
        float invl = 1.0f / l1;
        #pragma unroll
        for (int n = 0; n < 8; ++n) {
            half4 hv;
            hv[0] = (f16)(o1[n][0] * invl); hv[1] = (f16)(o1[n][1] * invl);
            hv[2] = (f16)(o1[n][2] * invl); hv[3] = (f16)(o1[n][3] * invl);
            *reinterpret_cast<half4*>(
                &O[((size_t)(b * T_ + qg1) * NH + h) * DH + n*16 + g*4]) = hv;
        }
    }
#undef PV
#undef PFRAG
#undef SMAX
#undef QKT
#undef STAGE_K
#undef STAGE_V
}

// ---------------- launch ----------------
extern "C" void kernel_launch(void* const* d_in, const int* in_sizes, int n_in,
                              void* d_out, int out_size, void* d_ws, size_t ws_size,
                              hipStream_t stream)
{
    const float* x  = (const float*)d_in[0];
    const float* wq = (const float*)d_in[1];
    const float* wk = (const float*)d_in[2];
    const float* wv = (const float*)d_in[3];
    const float* wo = (const float*)d_in[4];
    float* out = (float*)d_out;

    const size_t nx = (size_t)M_ * DM;   // 8388608
    const size_t nw = (size_t)DM * DM;   // 4194304
    const size_t need = (nx * 5 + nw * 4) * sizeof(f16);  // ~117 MB
    if (ws_size < need) return;

    char* ws = (char*)d_ws;
    f16* xh  = (f16*)ws;  ws += nx * 2;
    f16* wqh = (f16*)ws;  ws += nw * 2;   // wq,wk,wv contiguous -> fused B [6144,2048]
    f16* wkh = (f16*)ws;  ws += nw * 2;
    f16* wvh = (f16*)ws;  ws += nw * 2;
    f16* woh = (f16*)ws;  ws += nw * 2;
    f16* Qh  = (f16*)ws;  ws += nx * 2;   // Q,K contiguous; V slot holds V^T [B,H,DH,T]
    f16* Kh  = (f16*)ws;  ws += nx * 2;
    f16* Vh  = (f16*)ws;  ws += nx * 2;   // written transposed by qkv3 epilogue
    f16* Oh  = (f16*)ws;  ws += nx * 2;
    (void)Kh;

    CvtArgs ca;
    ca.s[0] = x;  ca.d[0] = xh;
    ca.s[1] = wq; ca.d[1] = wqh;
    ca.s[2] = wk; ca.d[2] = wkh;
    ca.s[3] = wv; ca.d[3] = wvh;
    ca.s[4] = wo; ca.d[4] = woh;
    convert_all<<<24576, 256, 0, stream>>>(ca);

    qkv3<<<dim3(512), 512, 0, stream>>>(xh, wqh, Qh);   // V written transposed

    attn_fwd<<<dim3(512), 256, 0, stream>>>(Qh, Kh, Vh, Oh);

    wo2<<<dim3(256), 512, 0, stream>>>(Oh, woh, out);
}

// Round 14
// 228.216 us; speedup vs baseline: 1.1119x; 1.1119x over previous
//
#include <hip/hip_runtime.h>
#include <hip/hip_bf16.h>
#include <hip/hip_fp16.h>

// Problem constants
#define B_   2
#define T_   2048
#define DM   2048
#define NH   16
#define DH   128
#define M_   (B_*T_)          // 4096 rows
#define SCALE_ 0.08838834764831845f   // 1/sqrt(128)

typedef _Float16 f16;
typedef f16  half8 __attribute__((ext_vector_type(8)));
typedef f16  half4 __attribute__((ext_vector_type(4)));
typedef float f32x4 __attribute__((ext_vector_type(4)));

#define GL16(gp, lp) __builtin_amdgcn_global_load_lds( \
    (const __attribute__((address_space(1))) void*)(gp), \
    (__attribute__((address_space(3))) void*)(lp), 16, 0, 0)

#define MFMA16(a, b, c) __builtin_amdgcn_mfma_f32_16x16x32_f16((a), (b), (c), 0, 0, 0)

// ---------------- fused fp32 -> fp16 convert (one launch for all 5) ----------------
struct CvtArgs { const float* s[5]; f16* d[5]; };

__global__ __launch_bounds__(256) void convert_all(CvtArgs a) {
    size_t i4 = (size_t)blockIdx.x * 256 + threadIdx.x;
    int r; size_t off;
    if (i4 < 2097152) { r = 0; off = i4; }
    else { size_t k = i4 - 2097152; r = 1 + (int)(k >> 20); off = k & 1048575; }
    float4 v = *((const float4*)a.s[r] + off);
    half4 h;
    h[0] = (f16)v.x; h[1] = (f16)v.y; h[2] = (f16)v.z; h[3] = (f16)v.w;
    *((half4*)a.d[r] + off) = h;
}

// ============ fused QKV GEMM: 256x192, BK=64 (R3 version — best measured, frozen) ============
// R13 lesson: fusing V-transpose into this epilogue scatters lane-adjacent
// writes to 4KB stride (2B/cacheline) -> +35 us. Transpose needs the LDS
// bounce that standalone vtrans provides. Normal [B,H,T,DH] writes restored.
#define NT_K 32

__global__ __launch_bounds__(512, 2)
void qkv3(const f16* __restrict__ A, const f16* __restrict__ Bw,
          f16* __restrict__ dst)
{
    __shared__ __align__(16) char smem[114688];   // 2 x (32KB A + 24KB B)

    const int tid  = threadIdx.x;
    const int lane = tid & 63;
    const int w    = tid >> 6;
    const int wr   = w >> 1, wc = w & 1;          // 4x2 wave grid

    const int id = (blockIdx.x & 7) * 64 + (blockIdx.x >> 3);
    const int bm = id & 15, bn = id >> 4;
    const int m0 = bm * 256, n0 = bn * 192;

    const int scol8 = (((tid & 7) ^ ((tid >> 3) & 7)) << 3);
    const int rc0 = (((lane >> 4) * 16)      ) ^ ((lane & 7) << 4);
    const int rc1 = (64 + (lane >> 4) * 16   ) ^ ((lane & 7) << 4);

    f32x4 acc[4][6] = {};

#define QSTAGE_A(bufb, ch, s, kt) GL16( \
    A + (size_t)(m0 + (ch)*128 + (tid>>8)*64 + (s)*32 + ((tid>>3)&31)) * 2048 + (kt)*64 + scol8, \
    smem + (bufb)*57344 + (ch)*16384 + (s)*8192 + w*1024)
#define QSTAGE_B(bufb, u, kt) GL16( \
    Bw + (size_t)(n0 + (tid>>7)*48 + (u)*16 + ((tid>>3)&15)) * 2048 + (kt)*64 + scol8, \
    smem + (bufb)*57344 + 32768 + (u)*8192 + w*1024)

    const int abase = (wr >> 1) * 16384 + (wr & 1) * 4096 + (lane & 15) * 128;
    const int bbase = 32768 + wc * 4096 + (lane & 15) * 128;

    half8 af0[4][2], af1[4][2], bnx[2];

    QSTAGE_A(0, 0, 0, 0); QSTAGE_A(0, 0, 1, 0);
    QSTAGE_A(0, 1, 0, 0); QSTAGE_A(0, 1, 1, 0);
    QSTAGE_B(0, 0, 0);    QSTAGE_B(0, 1, 0);    QSTAGE_B(0, 2, 0);
    {
        asm volatile("s_waitcnt vmcnt(2)" ::: "memory");
        __builtin_amdgcn_s_barrier();
        __builtin_amdgcn_sched_barrier(0);
        const char* buf0 = smem;
        #pragma unroll
        for (int m = 0; m < 4; ++m) {
            const char* p = buf0 + (m >> 1) * 8192 + abase + (m & 1) * 2048;
            af0[m][0] = *(const half8*)(p + rc0);
            af0[m][1] = *(const half8*)(p + rc1);
        }
        bnx[0] = *(const half8*)(buf0 + bbase + rc0);
        bnx[1] = *(const half8*)(buf0 + bbase + rc1);
    }

#define GATE(n_) do { \
    asm volatile("s_waitcnt vmcnt(" #n_ ")" ::: "memory"); \
    __builtin_amdgcn_s_barrier(); \
    __builtin_amdgcn_sched_barrier(0); \
} while (0)

#define MFC(AF, BB, f_) do { \
    __builtin_amdgcn_s_setprio(1); \
    _Pragma("unroll") \
    for (int m_ = 0; m_ < 4; ++m_) { \
        acc[m_][f_] = MFMA16(AF[m_][0], (BB)[0], acc[m_][f_]); \
        acc[m_][f_] = MFMA16(AF[m_][1], (BB)[1], acc[m_][f_]); \
    } \
    __builtin_amdgcn_s_setprio(0); \
} while (0)

#define RDB(dstv, off) do { \
    const char* p_ = buf + bbase + (off); \
    dstv[0] = *(const half8*)(p_ + rc0); \
    dstv[1] = *(const half8*)(p_ + rc1); \
} while (0)

#define BODY(t_, c_, AFC, AFN) do { \
    const char* buf  = smem + (c_) * 57344; \
    const char* nbuf = smem + ((c_) ^ 1) * 57344; \
    const int  kt    = ((t_) + 1 < NT_K) ? (t_) + 1 : (t_); \
    half8 b3[2], b1[2], b4[2], b2[2], b5[2]; \
    /* ph0: reads b(f3); stage A0',A1'; MFMA f0 */ \
    RDB(b3, 2048); \
    QSTAGE_A((c_) ^ 1, 0, 0, kt); QSTAGE_A((c_) ^ 1, 0, 1, kt); \
    MFC(AFC, bnx, 0); \
    /* ph1: gate B1; reads b(f1); stage A2',A3'; MFMA f3 */ \
    GATE(3); \
    RDB(b1, 8192); \
    QSTAGE_A((c_) ^ 1, 1, 0, kt); QSTAGE_A((c_) ^ 1, 1, 1, kt); \
    MFC(AFC, b3, 3); \
    /* ph2: reads b(f4); stage B0'; MFMA f1 */ \
    RDB(b4, 8192 + 2048); \
    QSTAGE_B((c_) ^ 1, 0, kt); \
    MFC(AFC, b1, 1); \
    /* ph3: gate B2; reads b(f2); stage B1'; MFMA f4 */ \
    GATE(5); \
    RDB(b2, 16384); \
    QSTAGE_B((c_) ^ 1, 1, kt); \
    MFC(AFC, b4, 4); \
    /* ph4: gate A0-3'+B0'; reads b(f5)+af'[0..1]; stage B2'; MFMA f2 */ \
    GATE(1); \
    RDB(b5, 16384 + 2048); \
    { const char* p_ = nbuf + abase; \
      AFN[0][0] = *(const half8*)(p_ + rc0); \
      AFN[0][1] = *(const half8*)(p_ + rc1); \
      AFN[1][0] = *(const half8*)(p_ + 2048 + rc0); \
      AFN[1][1] = *(const half8*)(p_ + 2048 + rc1); } \
    QSTAGE_B((c_) ^ 1, 2, kt); \
    MFC(AFC, b2, 2); \
    /* ph5: reads af'[2..3] + b'(f0); MFMA f5 */ \
    { const char* p_ = nbuf + 8192 + abase; \
      AFN[2][0] = *(const half8*)(p_ + rc0); \
      AFN[2][1] = *(const half8*)(p_ + rc1); \
      AFN[3][0] = *(const half8*)(p_ + 2048 + rc0); \
      AFN[3][1] = *(const half8*)(p_ + 2048 + rc1); } \
    { const char* p_ = nbuf + bbase; \
      bnx[0] = *(const half8*)(p_ + rc0); \
      bnx[1] = *(const half8*)(p_ + rc1); } \
    MFC(AFC, b5, 5); \
} while (0)

    for (int t = 0; t < NT_K; t += 2) {
        BODY(t,     0, af0, af1);
        BODY(t + 1, 1, af1, af0);
    }
#undef BODY
#undef RDB
#undef MFC
#undef GATE
#undef QSTAGE_A
#undef QSTAGE_B

    asm volatile("s_waitcnt vmcnt(0)" ::: "memory");

    #pragma unroll
    for (int m = 0; m < 4; ++m)
        #pragma unroll
        for (int f = 0; f < 6; ++f)
            #pragma unroll
            for (int j = 0; j < 4; ++j) {
                int row  = m0 + wr * 64 + m * 16 + (lane >> 4) * 4 + j;
                int gcol = n0 + wc * 96 + f * 16 + (lane & 15);
                int sec = gcol >> 11, cic = gcol & 2047;
                int b = row >> 11, tt = row & (T_ - 1);
                int h = cic >> 7, d = cic & 127;
                float cs = (sec == 0) ? SCALE_ : 1.0f;
                dst[(size_t)sec * ((size_t)M_ * 2048) +
                    ((size_t)(b * NH + h) * T_ + tt) * DH + d] = (f16)(acc[m][f][j] * cs);
            }
}

// ============ W_o GEMM: 256x128, BK=64, 2-gate (R9 version — best measured) ============
#define NT_W 32

__global__ __launch_bounds__(512, 2)
void wo2(const f16* __restrict__ A, const f16* __restrict__ Bw,
         float* __restrict__ Cf)
{
    __shared__ __align__(16) char smem[98304];   // 2 x (32KB A + 16KB B)

    const int tid  = threadIdx.x;
    const int lane = tid & 63;
    const int w    = tid >> 6;
    const int wr   = w >> 1, wc = w & 1;          // 4x2 wave grid, wave 64x64

    const int id = (blockIdx.x & 7) * 32 + (blockIdx.x >> 3);
    const int bm = id & 15, bn = id >> 4;
    const int m0 = bm * 256, n0 = bn * 128;

    const int scol8 = (((tid & 7) ^ ((tid >> 3) & 7)) << 3);
    const int rc0 = (((lane >> 4) * 16)      ) ^ ((lane & 7) << 4);
    const int rc1 = (64 + (lane >> 4) * 16   ) ^ ((lane & 7) << 4);

    f32x4 acc[4][4] = {};

#define WSA(bufb, s, kt) GL16( \
    A + (size_t)(m0 + ((s)&1)*128 + (tid>>8)*64 + ((s)>>1)*32 + ((tid>>3)&31)) * 2048 + (kt)*64 + scol8, \
    smem + (bufb)*49152 + (s)*8192 + w*1024)
#define WSB(bufb, u, kt) GL16( \
    Bw + (size_t)(n0 + (tid>>8)*64 + (u)*32 + ((tid>>3)&31)) * 2048 + (kt)*64 + scol8, \
    smem + (bufb)*49152 + 32768 + (u)*8192 + w*1024)

    WSA(0, 0, 0); WSA(0, 1, 0); WSB(0, 0, 0); WSB(0, 1, 0);
    WSA(0, 2, 0); WSA(0, 3, 0);

    const int abase = (wr >> 1) * 8192 + (wr & 1) * 4096 + (lane & 15) * 128;
    const int bbase = 32768 + wc * 4096 + (lane & 15) * 128;

#define WGATE(n_) do { \
    asm volatile("s_waitcnt vmcnt(" #n_ ")" ::: "memory"); \
    __builtin_amdgcn_s_barrier(); \
    __builtin_amdgcn_sched_barrier(0); \
} while (0)

    for (int t = 0; t < NT_W; ++t) {
        const int c = t & 1;
        const char* buf = smem + c * 49152;
        const int kt = (t + 1 < NT_W) ? t + 1 : t;

        half8 af[4][2], bf[4][2];

        // ---- phase 0: m=0,1 ----
        WGATE(2);
        #pragma unroll
        for (int m = 0; m < 2; ++m) {
            const char* p = buf + abase + m * 2048;
            af[m][0] = *(const half8*)(p + rc0);
            af[m][1] = *(const half8*)(p + rc1);
        }
        #pragma unroll
        for (int n = 0; n < 4; ++n) {
            const char* p = buf + bbase + (n >> 1) * 8192 + (n & 1) * 2048;
            bf[n][0] = *(const half8*)(p + rc0);
            bf[n][1] = *(const half8*)(p + rc1);
        }
        WSA(c ^ 1, 0, kt); WSA(c ^ 1, 1, kt);
        WSB(c ^ 1, 0, kt); WSB(c ^ 1, 1, kt);
        __builtin_amdgcn_s_setprio(1);
        #pragma unroll
        for (int m = 0; m < 2; ++m)
            #pragma unroll
            for (int n = 0; n < 4; ++n) {
                acc[m][n] = MFMA16(af[m][0], bf[n][0], acc[m][n]);
                acc[m][n] = MFMA16(af[m][1], bf[n][1], acc[m][n]);
            }
        __builtin_amdgcn_s_setprio(0);

        // ---- phase 1: m=2,3 ----
        WGATE(4);
        #pragma unroll
        for (int m = 2; m < 4; ++m) {
            const char* p = buf + 16384 + abase + (m & 1) * 2048;
            af[m][0] = *(const half8*)(p + rc0);
            af[m][1] = *(const half8*)(p + rc1);
        }
        WSA(c ^ 1, 2, kt); WSA(c ^ 1, 3, kt);
        __builtin_amdgcn_s_setprio(1);
        #pragma unroll
        for (int m = 2; m < 4; ++m)
            #pragma unroll
            for (int n = 0; n < 4; ++n) {
                acc[m][n] = MFMA16(af[m][0], bf[n][0], acc[m][n]);
                acc[m][n] = MFMA16(af[m][1], bf[n][1], acc[m][n]);
            }
        __builtin_amdgcn_s_setprio(0);
    }
#undef WGATE
#undef WSA
#undef WSB

    asm volatile("s_waitcnt vmcnt(0)" ::: "memory");

    #pragma unroll
    for (int m = 0; m < 4; ++m)
        #pragma unroll
        for (int n = 0; n < 4; ++n)
            #pragma unroll
            for (int j = 0; j < 4; ++j) {
                int row = m0 + wr * 64 + m * 16 + (lane >> 4) * 4 + j;
                int col = n0 + wc * 64 + n * 16 + (lane & 15);
                Cf[(size_t)row * 2048 + col] = acc[m][n][j];
            }
}

// ---------------- V transpose: [B,H,T,DH] -> [B,H,DH,T] ----------------
__global__ __launch_bounds__(256)
void vtrans(const f16* __restrict__ Vin, f16* __restrict__ Vout)
{
    __shared__ f16 ld[64][72];
    const int tid = threadIdx.x;
    const int dd = blockIdx.x;          // 0..1  (d-half)
    const int tt = blockIdx.y;          // 0..31 (t-tile)
    const int bh = blockIdx.z;          // 0..31

    const int r  = tid >> 2;            // 0..63
    const int s2 = (tid & 3) * 2;       // seg pair: 0,2,4,6

    const f16* src = Vin + ((size_t)bh * T_ + tt * 64 + r) * DH + dd * 64;
    half8 v0 = *(const half8*)(src + s2 * 8);
    half8 v1 = *(const half8*)(src + s2 * 8 + 8);
    #pragma unroll
    for (int e = 0; e < 8; ++e) ld[s2 * 8 + e][r]     = v0[e];
    #pragma unroll
    for (int e = 0; e < 8; ++e) ld[s2 * 8 + 8 + e][r] = v1[e];
    __syncthreads();

    f16* dst = Vout + ((size_t)bh * DH + dd * 64 + r) * T_ + tt * 64;
    *(half8*)(dst + s2 * 8)     = *(const half8*)&ld[r][s2 * 8];
    *(half8*)(dst + s2 * 8 + 8) = *(const half8*)&ld[r][s2 * 8 + 8];
}

// ---------------- causal flash attention: mirror-pair + softmax cuts (R7 exact) ----------------
#define QB 64
#define KB 64
#define PP 72
#define NQT (T_/QB)   // 32

__global__ __launch_bounds__(256, 2)
void attn_fwd(const f16* __restrict__ Q, const f16* __restrict__ K,
              const f16* __restrict__ Vt, f16* __restrict__ O)
{
    __shared__ __align__(16) char Ks[2][16384];   // 64 k-rows x 256B (swz)
    __shared__ __align__(16) char Vs[2][16384];   // 128 d-rows x 128B (swz)
    __shared__ __align__(16) f16 Ps[4][16][PP];

    const int tid  = threadIdx.x;
    const int lane = tid & 63;
    const int w    = tid >> 6;
    const int g    = lane >> 4;

    const int bid  = blockIdx.x;
    const int swz  = (bid & 7) * 64 + (bid >> 3);
    const int bh   = swz >> 4;
    const int pair = swz & 15;
    const size_t base = (size_t)bh * T_ * DH;     // == bh*DH*T_ (V^T base)
    const int b = bh >> 4, h = bh & 15;

    const int krow0 = w * 4 + g;
    const int kswz  = ((lane & 15) ^ (krow0 & 7)) << 3;          // elems
    const int vrow0 = w * 8 + (lane >> 3);
    const int vswz  = (((lane & 7) ^ ((lane >> 3) & 7)) << 3);   // elems

#define STAGE_K(c_, kv) do { \
    _Pragma("unroll") for (int i_ = 0; i_ < 4; ++i_) { \
        const f16* g_ = K + base + (size_t)((kv) + i_*16 + krow0) * DH + kswz; \
        GL16(g_, &Ks[c_][i_*4096 + w*1024]); } } while (0)
#define STAGE_V(c_, kv) do { \
    _Pragma("unroll") for (int i_ = 0; i_ < 4; ++i_) { \
        const f16* g_ = Vt + base + (size_t)(i_*32 + vrow0) * T_ + (kv) + vswz; \
        GL16(g_, &Vs[c_][i_*4096 + w*1024]); } } while (0)

#define QKT(SA, QF) do { \
    __builtin_amdgcn_s_setprio(1); \
    _Pragma("unroll") \
    for (int n_ = 0; n_ < 4; ++n_) \
        _Pragma("unroll") \
        for (int kk_ = 0; kk_ < 4; ++kk_) { \
            half8 kfv = *(const half8*)(kb + (n_*16 + (lane & 15)) * 256 + \
                ((kk_*32 + g * 8) * 2 ^ ((lane & 7) << 4))); \
            SA[n_] = MFMA16(kfv, QF[kk_], SA[n_]); \
        } \
    __builtin_amdgcn_s_setprio(0); \
} while (0)

#define SMAX(SA, MRUN, LSUM, OO) do { \
    float mx_ = SA[0][0]; \
    _Pragma("unroll") \
    for (int n_ = 0; n_ < 4; ++n_) \
        _Pragma("unroll") \
        for (int j_ = 0; j_ < 4; ++j_) mx_ = fmaxf(mx_, SA[n_][j_]); \
    mx_ = fmaxf(mx_, __shfl_xor(mx_, 16)); \
    mx_ = fmaxf(mx_, __shfl_xor(mx_, 32)); \
    if (!__all(mx_ <= MRUN + 5.f)) { \
        float mnew_ = fmaxf(MRUN, mx_); \
        float sf_ = __expf(MRUN - mnew_); \
        _Pragma("unroll") \
        for (int nn_ = 0; nn_ < 8; ++nn_) OO[nn_] *= sf_; \
        LSUM *= sf_; \
        MRUN = mnew_; \
    } \
    float rs_ = 0.f; \
    _Pragma("unroll") \
    for (int n_ = 0; n_ < 4; ++n_) \
        _Pragma("unroll") \
        for (int j_ = 0; j_ < 4; ++j_) { \
            float p_ = __expf(SA[n_][j_] - MRUN); \
            SA[n_][j_] = p_; \
            rs_ += p_; \
        } \
    LSUM += rs_; \
} while (0)

#define PFRAG(SA, BP) do { \
    _Pragma("unroll") \
    for (int n_ = 0; n_ < 4; ++n_) { \
        half4 hv_; \
        hv_[0] = (f16)SA[n_][0]; hv_[1] = (f16)SA[n_][1]; \
        hv_[2] = (f16)SA[n_][2]; hv_[3] = (f16)SA[n_][3]; \
        *reinterpret_cast<half4*>(&Ps[w][lane & 15][n_*16 + g*4]) = hv_; \
    } \
    _Pragma("unroll") \
    for (int cc_ = 0; cc_ < 2; ++cc_) \
        BP[cc_] = *reinterpret_cast<const half8*>(&Ps[w][lane & 15][cc_*32 + g*8]); \
} while (0)

#define PV(OO, BP) do { \
    __builtin_amdgcn_s_setprio(1); \
    _Pragma("unroll") \
    for (int n_ = 0; n_ < 8; ++n_) \
        _Pragma("unroll") \
        for (int cc_ = 0; cc_ < 2; ++cc_) { \
            half8 vf_ = *(const half8*)(vb + (n_*16 + (lane & 15)) * 128 + \
                ((cc_*64 + g*16) ^ ((lane & 7) << 4))); \
            OO[n_] = MFMA16(vf_, BP[cc_], OO[n_]); \
        } \
    __builtin_amdgcn_s_setprio(0); \
} while (0)

    const int qt1 = pair;              // small member
    const int qt2 = NQT - 1 - pair;    // big member
    const int nt1 = qt1 + 1;           // set1 kv-tiles
    const int ntU = qt2 + 1;           // union kv-tiles (= set2's)
    const int qg1 = qt1 * QB + w * 16 + (lane & 15);
    const int qg2 = qt2 * QB + w * 16 + (lane & 15);

    half8 qf1[4], qf2[4];
    #pragma unroll
    for (int kk = 0; kk < 4; ++kk) {
        qf1[kk] = *reinterpret_cast<const half8*>(
            &Q[base + (size_t)qg1 * DH + kk * 32 + g * 8]);
        qf2[kk] = *reinterpret_cast<const half8*>(
            &Q[base + (size_t)qg2 * DH + kk * 32 + g * 8]);
    }

    float mrun1 = -1e30f, lsum1 = 0.f;
    float mrun2 = -1e30f, lsum2 = 0.f;
    f32x4 o1[8] = {};
    f32x4 o2[8] = {};

    STAGE_K(0, 0);
    STAGE_V(0, 0);

    for (int it = 0; it < ntU; ++it) {
        const int c = it & 1;
        __syncthreads();      // vmcnt(0) drain: tile-it K/V resident
        if (it + 1 < ntU) {
            STAGE_K(c ^ 1, (it + 1) * KB);
            STAGE_V(c ^ 1, (it + 1) * KB);
        }
        const bool s1 = (it < nt1);    // block-uniform
        const char* kb = &Ks[c][0];
        const char* vb = &Vs[c][0];

        f32x4 sa2[4] = {};
        f32x4 sa1[4] = {};

        QKT(sa2, qf2);
        if (s1) QKT(sa1, qf1);

        if (it == ntU - 1) {
            #pragma unroll
            for (int n = 0; n < 4; ++n)
                #pragma unroll
                for (int j = 0; j < 4; ++j) {
                    int kg = it * KB + n*16 + g*4 + j;
                    if (kg > qg2) sa2[n][j] = -1e30f;
                }
        }
        if (s1 && it == nt1 - 1) {
            #pragma unroll
            for (int n = 0; n < 4; ++n)
                #pragma unroll
                for (int j = 0; j < 4; ++j) {
                    int kg = it * KB + n*16 + g*4 + j;
                    if (kg > qg1) sa1[n][j] = -1e30f;
                }
        }

        SMAX(sa2, mrun2, lsum2, o2);
        half8 bp2[2];
        PFRAG(sa2, bp2);
        PV(o2, bp2);

        if (s1) {
            SMAX(sa1, mrun1, lsum1, o1);
            half8 bp1[2];
            PFRAG(sa1, bp1);
            PV(o1, bp1);
        }
    }

    {
        float l2 = lsum2;
        l2 += __shfl_xor(l2, 16);
        l2 += __shfl_xor(l2, 32);
        float invl = 1.0f / l2;
        #pragma unroll
        for (int n = 0; n < 8; ++n) {
            half4 hv;
            hv[0] = (f16)(o2[n][0] * invl); hv[1] = (f16)(o2[n][1] * invl);
            hv[2] = (f16)(o2[n][2] * invl); hv[3] = (f16)(o2[n][3] * invl);
            *reinterpret_cast<half4*>(
                &O[((size_t)(b * T_ + qg2) * NH + h) * DH + n*16 + g*4]) = hv;
        }
    }
    {
        float l1 = lsum1;
        l1 += __shfl_xor(l1, 16);
        l1 += __shfl_xor(l1, 32);
        float invl = 1.0f / l1;
        #pragma unroll
        for (int n = 0; n < 8; ++n) {
            half4 hv;
            hv[0] = (f16)(o1[n][0] * invl); hv[1] = (f16)(o1[n][1] * invl);
            hv[2] = (f16)(o1[n][2] * invl); hv[3] = (f16)(o1[n][3] * invl);
            *reinterpret_cast<half4*>(
                &O[((size_t)(b * T_ + qg1) * NH + h) * DH + n*16 + g*4]) = hv;
        }
    }
#undef PV
#undef PFRAG
#undef SMAX
#undef QKT
#undef STAGE_K
#undef STAGE_V
}

// ---------------- launch ----------------
extern "C" void kernel_launch(void* const* d_in, const int* in_sizes, int n_in,
                              void* d_out, int out_size, void* d_ws, size_t ws_size,
                              hipStream_t stream)
{
    const float* x  = (const float*)d_in[0];
    const float* wq = (const float*)d_in[1];
    const float* wk = (const float*)d_in[2];
    const float* wv = (const float*)d_in[3];
    const float* wo = (const float*)d_in[4];
    float* out = (float*)d_out;

    const size_t nx = (size_t)M_ * DM;   // 8388608
    const size_t nw = (size_t)DM * DM;   // 4194304
    const size_t need = (nx * 5 + nw * 4) * sizeof(f16);  // ~117 MB
    if (ws_size < need) return;

    char* ws = (char*)d_ws;
    f16* xh  = (f16*)ws;  ws += nx * 2;   // after qkv3: dead -> reused as V^T
    f16* wqh = (f16*)ws;  ws += nw * 2;   // wq,wk,wv contiguous -> fused B [6144,2048]
    f16* wkh = (f16*)ws;  ws += nw * 2;
    f16* wvh = (f16*)ws;  ws += nw * 2;
    f16* woh = (f16*)ws;  ws += nw * 2;
    f16* Qh  = (f16*)ws;  ws += nx * 2;   // Q,K,V contiguous -> fused dst
    f16* Kh  = (f16*)ws;  ws += nx * 2;
    f16* Vh  = (f16*)ws;  ws += nx * 2;
    f16* Oh  = (f16*)ws;  ws += nx * 2;

    f16* Vth = xh;   // V^T [B,H,DH,T] aliases xh (x consumed by qkv3 first)

    CvtArgs ca;
    ca.s[0] = x;  ca.d[0] = xh;
    ca.s[1] = wq; ca.d[1] = wqh;
    ca.s[2] = wk; ca.d[2] = wkh;
    ca.s[3] = wv; ca.d[3] = wvh;
    ca.s[4] = wo; ca.d[4] = woh;
    convert_all<<<24576, 256, 0, stream>>>(ca);

    qkv3<<<dim3(512), 512, 0, stream>>>(xh, wqh, Qh);

    vtrans<<<dim3(2, 32, 32), 256, 0, stream>>>(Vh, Vth);

    attn_fwd<<<dim3(512), 256, 0, stream>>>(Qh, Kh, Vth, Oh);

    wo2<<<dim3(256), 512, 0, stream>>>(Oh, woh, out);
}